// Round 13
// baseline (161.114 us; speedup 1.0000x reference)
//
#include <hip/hip_runtime.h>
#include <hip/hip_bf16.h>
#include <stdint.h>
#include <stddef.h>

#define NROWS 8192
#define DDIM  512              // floats per input row; ALSO bytes per fp8 row
#define TILE  128
#define BKB   128              // fp8 K-bytes per stage (4 stages)
#define NBLK  (NROWS / TILE)   // 64

static_assert(NBLK == 64, "bj extraction assumes 64 col-blocks");

typedef float f32x4 __attribute__((ext_vector_type(4)));
typedef long  v2l  __attribute__((ext_vector_type(2)));   // one 16-B load (2 MFMA operands)

// async global->LDS, 16B per lane; LDS dest is wave-uniform base + lane*16
__device__ __forceinline__ void async_copy16(const void* g, void* l) {
    __builtin_amdgcn_global_load_lds(
        (const __attribute__((address_space(1))) uint32_t*)g,
        (__attribute__((address_space(3))) uint32_t*)l,
        16, 0, 0);
}

// -------- prep: zero accumulators + normalize both matrices to fp8 e4m3 --------
// grid = 4096: blocks [0,2048) cxr->cn8, [2048,4096) ehr->en8.
// blocks [0,64) zero rowsum/colsum (64*256 = 16384 = 2N floats); block 0 zeroes out[0].
__global__ __launch_bounds__(256) void prep_kernel(
    const float* __restrict__ CXR, const float* __restrict__ EHR,
    uint32_t* __restrict__ CN8, uint32_t* __restrict__ EN8,
    float* __restrict__ rowsum /* colsum follows contiguously */,
    float* __restrict__ out)
{
    if (blockIdx.x < 64) {
        rowsum[blockIdx.x * 256 + threadIdx.x] = 0.f;
        if (blockIdx.x == 0 && threadIdx.x == 0) out[0] = 0.f;
    }
    const int half = (blockIdx.x >= 2048);
    const float* X = half ? EHR : CXR;
    uint32_t* Y = half ? EN8 : CN8;
    const int row  = (blockIdx.x & 2047) * 4 + (threadIdx.x >> 6);
    const int lane = threadIdx.x & 63;
    const float* xr = X + (size_t)row * DDIM;
    float4 v0 = ((const float4*)xr)[lane];        // elems lane*4   .. +3
    float4 v1 = ((const float4*)xr)[lane + 64];   // elems 256+lane*4 .. +3
    float ss = v0.x*v0.x + v0.y*v0.y + v0.z*v0.z + v0.w*v0.w
             + v1.x*v1.x + v1.y*v1.y + v1.z*v1.z + v1.w*v1.w;
    #pragma unroll
    for (int d = 1; d < 64; d <<= 1) ss += __shfl_xor(ss, d);
    const float sc = 1.0f / fmaxf(sqrtf(ss), 1e-8f);
    uint32_t* yr = Y + (size_t)row * (DDIM / 4);
    int w0 = __builtin_amdgcn_cvt_pk_fp8_f32(v0.x*sc, v0.y*sc, 0, false);
    w0     = __builtin_amdgcn_cvt_pk_fp8_f32(v0.z*sc, v0.w*sc, w0, true);
    int w1 = __builtin_amdgcn_cvt_pk_fp8_f32(v1.x*sc, v1.y*sc, 0, false);
    w1     = __builtin_amdgcn_cvt_pk_fp8_f32(v1.z*sc, v1.w*sc, w1, true);
    yr[lane]      = (uint32_t)w0;   // bytes = elems lane*4..+3 in k order
    yr[lane + 64] = (uint32_t)w1;
}

// -------- fused S = cn·enT fp8 GEMM (restructured K-loop) + loss epilogue -----------
// RESTRUCTURE vs round 7 (65 us plateau): A-operand goes DIRECT global->VGPR
// (each lane loads its own fragments: one dwordx4 covers 16 rows x 64 B --
// coalesced, L2-served), prefetched one stage ahead. B keeps round-7's proven
// staging+swizzle (unit u at slot u^(r&7), fragment b128 at u=kk2*4+q --
// measured 0 conflicts) but DOUBLE-buffered (2x16 KB = same 32 KB footprint,
// occupancy preserved). One barrier per stage (4 total vs 8); every load
// drained at a barrier was issued BEFORE the preceding compute phase, so the
// vmcnt(0) drain waits on aged loads -- the structural fix the 2-barrier loop
// could not express. k-mapping: window 2kk2 lo-8B = global k0+(kk2*4+q)*16..+7
// identical on A (direct) and B (LDS) => dot products exact.
__global__ __launch_bounds__(256, 2) void gemm_loss_kernel(
    const uint8_t* __restrict__ A,   // cn fp8 [N][512 B]
    const uint8_t* __restrict__ B,   // en fp8 [N][512 B]
    const float* __restrict__ temp_p,
    float* __restrict__ rowsum,
    float* __restrict__ colsum,
    float* __restrict__ diagv)
{
    __shared__ uint8_t Bs[2][TILE * BKB];   // 2 x 16 KB

    const int tid  = threadIdx.x;
    const int lane = tid & 63;
    const int wv   = tid >> 6;          // wave 0..3
    const int wi   = (wv >> 1) * 64;    // wave row offset in tile
    const int wj   = (wv & 1) * 64;     // wave col offset in tile
    const int lcol = lane & 15;
    const int q    = lane >> 4;

    const int bi = blockIdx.x & (NBLK - 1);
    const int bj = blockIdx.x >> 6;
    const int row0 = bi * TILE;
    const int col0 = bj * TILE;

    // B staging: wave wv stages B rows [wv*32, wv*32+32), 4 copies of 8 rows
    const int sr = lane >> 3;            // row within 8-row chunk
    const int su = (lane & 7) ^ sr;      // 16B-unit fetched by this lane (swizzle inverse)
    const uint8_t* Bg = B + (size_t)(col0 + wv * 32 + sr) * DDIM + su * 16;

    // A direct-load pointers: lane (lcol,q) owns rows wi+mt*16+lcol, 16 B at q*16
    const uint8_t* aptr[4];
    #pragma unroll
    for (int mt = 0; mt < 4; ++mt)
        aptr[mt] = A + (size_t)(row0 + wi + mt * 16 + lcol) * DDIM + q * 16;

    // B fragment read offsets (loop-invariant): [kk2][nt]
    int boff[2][4];
    #pragma unroll
    for (int kk2 = 0; kk2 < 2; ++kk2)
        #pragma unroll
        for (int nt = 0; nt < 4; ++nt) {
            const int r = wj + nt * 16 + lcol;
            boff[kk2][nt] = r * BKB + (((kk2 * 4 + q) ^ (r & 7)) * 16);
        }

    f32x4 acc[4][4] = {};

    // prologue: issue B stage-0 DMA + load A stage-0 fragments, then one drain
    #pragma unroll
    for (int c = 0; c < 4; ++c)
        async_copy16(Bg + (size_t)(c * 8) * DDIM, &Bs[0][(wv * 32 + c * 8) * BKB]);
    v2l areg[2][4];
    #pragma unroll
    for (int kk2 = 0; kk2 < 2; ++kk2)
        #pragma unroll
        for (int mt = 0; mt < 4; ++mt)
            areg[kk2][mt] = *(const v2l*)(aptr[mt] + kk2 * 64);
    __syncthreads();   // drain B0 DMA + A0 loads

    #pragma unroll
    for (int s = 0; s < 4; ++s) {
        const int cur = s & 1;
        v2l anew[2][4];
        if (s < 3) {
            const int k1 = (s + 1) * BKB;
            // issue next B stage into the other buffer (its last reader was
            // compute(s-1), fenced by the barrier we just passed)
            #pragma unroll
            for (int c = 0; c < 4; ++c)
                async_copy16(Bg + (size_t)(c * 8) * DDIM + k1,
                             &Bs[cur ^ 1][(wv * 32 + c * 8) * BKB]);
            // prefetch next A fragments
            #pragma unroll
            for (int kk2 = 0; kk2 < 2; ++kk2)
                #pragma unroll
                for (int mt = 0; mt < 4; ++mt)
                    anew[kk2][mt] = *(const v2l*)(aptr[mt] + k1 + kk2 * 64);
        }
        // compute stage s (ages the loads just issued)
        #pragma unroll
        for (int kk2 = 0; kk2 < 2; ++kk2) {
            #pragma unroll
            for (int nt = 0; nt < 4; ++nt) {
                v2l b16 = *(const v2l*)&Bs[cur][boff[kk2][nt]];
                #pragma unroll
                for (int mt = 0; mt < 4; ++mt)
                    acc[mt][nt] = __builtin_amdgcn_mfma_f32_16x16x32_fp8_fp8(
                        areg[kk2][mt].x, b16.x, acc[mt][nt], 0, 0, 0);
                #pragma unroll
                for (int mt = 0; mt < 4; ++mt)
                    acc[mt][nt] = __builtin_amdgcn_mfma_f32_16x16x32_fp8_fp8(
                        areg[kk2][mt].y, b16.y, acc[mt][nt], 0, 0, 0);
            }
        }
        if (s < 3) {
            __syncthreads();   // drain B(s+1) DMA + A(s+1) loads (fully aged)
            #pragma unroll
            for (int kk2 = 0; kk2 < 2; ++kk2)
                #pragma unroll
                for (int mt = 0; mt < 4; ++mt)
                    areg[kk2][mt] = anew[kk2][mt];
        }
    }

    // ---- epilogue: e = exp(s - M), M = 1/T (max possible), diag excluded ----
    const float invT = 1.0f / temp_p[0];
    const float M = invT;

    float rs[4][4];   // per-lane row partials [mt][reg]
    float cs[4];      // per-lane col partials [nt]
    #pragma unroll
    for (int mt = 0; mt < 4; ++mt)
        #pragma unroll
        for (int r = 0; r < 4; ++r) rs[mt][r] = 0.f;
    #pragma unroll
    for (int nt = 0; nt < 4; ++nt) cs[nt] = 0.f;

    #pragma unroll
    for (int mt = 0; mt < 4; ++mt) {
        #pragma unroll
        for (int nt = 0; nt < 4; ++nt) {
            #pragma unroll
            for (int r = 0; r < 4; ++r) {
                // C/D layout: col = lane&15, row = quad*4 + reg  [m89/m91]
                const int gi = row0 + wi + mt * 16 + q * 4 + r;
                const int gj = col0 + wj + nt * 16 + lcol;
                const float sv = acc[mt][nt][r] * invT;
                float e;
                if (gi == gj) { diagv[gi] = sv; e = 0.f; }
                else          { e = __expf(sv - M); }
                rs[mt][r] += e;
                cs[nt]    += e;
            }
        }
    }

    // row sums: reduce across the 16 columns (lane bits 0..3)
    #pragma unroll
    for (int d = 1; d < 16; d <<= 1)
        #pragma unroll
        for (int mt = 0; mt < 4; ++mt)
            #pragma unroll
            for (int r = 0; r < 4; ++r)
                rs[mt][r] += __shfl_xor(rs[mt][r], d);

    // col sums: reduce across the 4 quads (lane bits 4..5)
    #pragma unroll
    for (int d = 16; d < 64; d <<= 1)
        #pragma unroll
        for (int nt = 0; nt < 4; ++nt)
            cs[nt] += __shfl_xor(cs[nt], d);

    if (lcol == 0) {
        #pragma unroll
        for (int mt = 0; mt < 4; ++mt)
            #pragma unroll
            for (int r = 0; r < 4; ++r)
                atomicAdd(&rowsum[row0 + wi + mt * 16 + q * 4 + r], rs[mt][r]);
    }
    if (q == 0) {
        #pragma unroll
        for (int nt = 0; nt < 4; ++nt)
            atomicAdd(&colsum[col0 + wj + nt * 16 + lcol], cs[nt]);
    }
}

// -------- final scalar: loss = mean_i( 2M + log(rowsum_i) + log(colsum_i) - 2*diag_i ) ----
__global__ __launch_bounds__(256) void finalize_kernel(
    const float* __restrict__ rowsum, const float* __restrict__ colsum,
    const float* __restrict__ diagv,  const float* __restrict__ temp_p,
    float* __restrict__ out)
{
    __shared__ float red[4];
    const float M = 1.0f / temp_p[0];
    const int i = blockIdx.x * 256 + threadIdx.x;
    float s = 2.f * M + logf(rowsum[i]) + logf(colsum[i]) - 2.f * diagv[i];
    #pragma unroll
    for (int d = 1; d < 64; d <<= 1) s += __shfl_xor(s, d);
    if ((threadIdx.x & 63) == 0) red[threadIdx.x >> 6] = s;
    __syncthreads();
    if (threadIdx.x == 0)
        atomicAdd(out, (red[0] + red[1] + red[2] + red[3]) / (float)NROWS);
}

extern "C" void kernel_launch(void* const* d_in, const int* in_sizes, int n_in,
                              void* d_out, int out_size, void* d_ws, size_t ws_size,
                              hipStream_t stream) {
    (void)in_sizes; (void)n_in; (void)out_size; (void)ws_size;
    const float* cxr    = (const float*)d_in[0];
    const float* ehr    = (const float*)d_in[1];
    const float* temp_p = (const float*)d_in[2];
    float* out = (float*)d_out;

    // workspace: rowsum[N] | colsum[N] | diag[N] | cn fp8 [N*512B] | en fp8 (~8.1 MB)
    float* rowsum = (float*)d_ws;
    float* colsum = rowsum + NROWS;
    float* diagv  = colsum + NROWS;
    uint32_t* cn8 = (uint32_t*)(diagv + NROWS);            // 16B-aligned (96 KB offset)
    uint32_t* en8 = cn8 + (size_t)NROWS * (DDIM / 4);
    const uint8_t* cnb = (const uint8_t*)cn8;
    const uint8_t* enb = (const uint8_t*)en8;

    prep_kernel<<<4096, 256, 0, stream>>>(cxr, ehr, cn8, en8, rowsum, out);
    gemm_loss_kernel<<<NBLK * NBLK, 256, 0, stream>>>(cnb, enb, temp_p, rowsum, colsum, diagv);
    finalize_kernel<<<NROWS / 256, 256, 0, stream>>>(rowsum, colsum, diagv, temp_p, out);
}

// Round 14
// 136.492 us; speedup vs baseline: 1.1804x; 1.1804x over previous
//
#include <hip/hip_runtime.h>
#include <hip/hip_bf16.h>
#include <stdint.h>
#include <stddef.h>

#define NROWS 8192
#define DDIM  512              // floats per input row; ALSO bytes per fp8 row
#define TILE  128
#define BKB   128              // fp8 K-elements (=bytes) per LDS stage
#define NBLK  (NROWS / TILE)   // 64

static_assert(NBLK == 64, "bj extraction assumes 64 col-blocks");

typedef float f32x4 __attribute__((ext_vector_type(4)));
typedef long  v2l  __attribute__((ext_vector_type(2)));   // one 16-B LDS read

// async global->LDS, 16B per lane; LDS dest is wave-uniform base + lane*16
__device__ __forceinline__ void async_copy16(const void* g, void* l) {
    __builtin_amdgcn_global_load_lds(
        (const __attribute__((address_space(1))) uint32_t*)g,
        (__attribute__((address_space(3))) uint32_t*)l,
        16, 0, 0);
}

// -------- prep: zero accumulators + normalize both matrices to fp8 e4m3 --------
// grid = 4096: blocks [0,2048) cxr->cn8, [2048,4096) ehr->en8.
// blocks [0,64) zero rowsum/colsum (64*256 = 16384 = 2N floats); block 0 zeroes out[0].
__global__ __launch_bounds__(256) void prep_kernel(
    const float* __restrict__ CXR, const float* __restrict__ EHR,
    uint32_t* __restrict__ CN8, uint32_t* __restrict__ EN8,
    float* __restrict__ rowsum /* colsum follows contiguously */,
    float* __restrict__ out)
{
    if (blockIdx.x < 64) {
        rowsum[blockIdx.x * 256 + threadIdx.x] = 0.f;
        if (blockIdx.x == 0 && threadIdx.x == 0) out[0] = 0.f;
    }
    const int half = (blockIdx.x >= 2048);
    const float* X = half ? EHR : CXR;
    uint32_t* Y = half ? EN8 : CN8;
    const int row  = (blockIdx.x & 2047) * 4 + (threadIdx.x >> 6);
    const int lane = threadIdx.x & 63;
    const float* xr = X + (size_t)row * DDIM;
    float4 v0 = ((const float4*)xr)[lane];        // elems lane*4   .. +3
    float4 v1 = ((const float4*)xr)[lane + 64];   // elems 256+lane*4 .. +3
    float ss = v0.x*v0.x + v0.y*v0.y + v0.z*v0.z + v0.w*v0.w
             + v1.x*v1.x + v1.y*v1.y + v1.z*v1.z + v1.w*v1.w;
    #pragma unroll
    for (int d = 1; d < 64; d <<= 1) ss += __shfl_xor(ss, d);
    const float sc = 1.0f / fmaxf(sqrtf(ss), 1e-8f);
    uint32_t* yr = Y + (size_t)row * (DDIM / 4);
    int w0 = __builtin_amdgcn_cvt_pk_fp8_f32(v0.x*sc, v0.y*sc, 0, false);
    w0     = __builtin_amdgcn_cvt_pk_fp8_f32(v0.z*sc, v0.w*sc, w0, true);
    int w1 = __builtin_amdgcn_cvt_pk_fp8_f32(v1.x*sc, v1.y*sc, 0, false);
    w1     = __builtin_amdgcn_cvt_pk_fp8_f32(v1.z*sc, v1.w*sc, w1, true);
    yr[lane]      = (uint32_t)w0;   // bytes = elems lane*4..+3 in k order
    yr[lane + 64] = (uint32_t)w1;
}

// -------- fused S = cn·enT fp8 GEMM (non-scaled 16x16x32) + exp + reductions --------
// ROUND-7 KERNEL (best measured: 65.1 us, MfmaUtil 42%, 0 conflicts, no spill).
// Structural note for posterity: rounds 8/10/11/12/13 attacked the ~50% stall
// (vmcnt(0)+s_barrier drain, short-K prologue) via full-K residency, higher
// occupancy, LDS double-buffering, the 2.3x MX MFMA pipe, and direct-to-VGPR
// A operands -- all neutral or regressions. Matches learn_hip m99-m141: the
// 2-barrier K-loop plateau is compiler-structural; the path beyond is
// hand-assembled fine-grained vmcnt scheduling (hipBLASLt-style), not HIP C++.
// 256 threads / 4 waves, wave tile 64x64, acc 4x4 f32x4 (AGPRs).
// Fragment reads: conflict-free b128 via k-permutation -- lane (m,q) reads
// 16 B at unit u=kk2*4+q, slot u^(r&7); lo 8 B feed MFMA window 2kk2, hi feed
// 2kk2+1 (same permutation on A and B => dot products unchanged).
__global__ __launch_bounds__(256, 2) void gemm_loss_kernel(
    const uint8_t* __restrict__ A,   // cn fp8 [N][512 B]
    const uint8_t* __restrict__ B,   // en fp8 [N][512 B]
    const float* __restrict__ temp_p,
    float* __restrict__ rowsum,
    float* __restrict__ colsum,
    float* __restrict__ diagv)
{
    __shared__ uint8_t As[TILE * BKB];   // 16 KB
    __shared__ uint8_t Bs[TILE * BKB];   // 16 KB

    const int tid  = threadIdx.x;
    const int lane = tid & 63;
    const int wv   = tid >> 6;          // wave 0..3
    const int wi   = (wv >> 1) * 64;    // wave row offset in tile
    const int wj   = (wv & 1) * 64;     // wave col offset in tile
    const int lcol = lane & 15;
    const int q    = lane >> 4;

    const int bi = blockIdx.x & (NBLK - 1);
    const int bj = blockIdx.x >> 6;
    const int row0 = bi * TILE;
    const int col0 = bj * TILE;

    // staging: wave wv loads rows [wv*32, wv*32+32) of both tiles, 4 chunks of 8 rows
    const int sr = lane >> 3;            // row within 8-row chunk
    const int su = (lane & 7) ^ sr;      // 16B-unit fetched by this lane (swizzle inverse)
    const uint8_t* Ag = A + (size_t)(row0 + wv * 32 + sr) * DDIM + su * 16;
    const uint8_t* Bg = B + (size_t)(col0 + wv * 32 + sr) * DDIM + su * 16;

    f32x4 acc[4][4] = {};

    for (int k0 = 0; k0 < DDIM; k0 += BKB) {   // 4 stages
        __syncthreads();   // previous stage's LDS reads done before overwrite
        #pragma unroll
        for (int c = 0; c < 4; ++c) {
            async_copy16(Ag + (size_t)(c * 8) * DDIM + k0, &As[(wv * 32 + c * 8) * BKB]);
            async_copy16(Bg + (size_t)(c * 8) * DDIM + k0, &Bs[(wv * 32 + c * 8) * BKB]);
        }
        __syncthreads();   // drains vmcnt before s_barrier

        #pragma unroll
        for (int kk2 = 0; kk2 < 2; ++kk2) {    // each kk2 covers two K=32 windows
            const int u = kk2 * 4 + q;         // this lane's 16B k-unit
            long aflo[4], afhi[4];
            #pragma unroll
            for (int mt = 0; mt < 4; ++mt) {
                const int r = wi + mt * 16 + lcol;
                v2l a16 = *(const v2l*)&As[r * BKB + (u ^ (r & 7)) * 16];
                aflo[mt] = a16.x; afhi[mt] = a16.y;
            }
            // B fragments streamed: one b128 feeds 8 MFMAs (2 windows x 4 m-tiles)
            #pragma unroll
            for (int nt = 0; nt < 4; ++nt) {
                const int r = wj + nt * 16 + lcol;
                v2l b16 = *(const v2l*)&Bs[r * BKB + (u ^ (r & 7)) * 16];
                #pragma unroll
                for (int mt = 0; mt < 4; ++mt)
                    acc[mt][nt] = __builtin_amdgcn_mfma_f32_16x16x32_fp8_fp8(
                        aflo[mt], b16.x, acc[mt][nt], 0, 0, 0);
                #pragma unroll
                for (int mt = 0; mt < 4; ++mt)
                    acc[mt][nt] = __builtin_amdgcn_mfma_f32_16x16x32_fp8_fp8(
                        afhi[mt], b16.y, acc[mt][nt], 0, 0, 0);
            }
        }
    }

    // ---- epilogue: e = exp(s - M), M = 1/T (max possible), diag excluded ----
    const float invT = 1.0f / temp_p[0];
    const float M = invT;

    float rs[4][4];   // per-lane row partials [mt][reg]
    float cs[4];      // per-lane col partials [nt]
    #pragma unroll
    for (int mt = 0; mt < 4; ++mt)
        #pragma unroll
        for (int r = 0; r < 4; ++r) rs[mt][r] = 0.f;
    #pragma unroll
    for (int nt = 0; nt < 4; ++nt) cs[nt] = 0.f;

    #pragma unroll
    for (int mt = 0; mt < 4; ++mt) {
        #pragma unroll
        for (int nt = 0; nt < 4; ++nt) {
            #pragma unroll
            for (int r = 0; r < 4; ++r) {
                // C/D layout: col = lane&15, row = quad*4 + reg  [m89/m91]
                const int gi = row0 + wi + mt * 16 + q * 4 + r;
                const int gj = col0 + wj + nt * 16 + lcol;
                const float sv = acc[mt][nt][r] * invT;
                float e;
                if (gi == gj) { diagv[gi] = sv; e = 0.f; }
                else          { e = __expf(sv - M); }
                rs[mt][r] += e;
                cs[nt]    += e;
            }
        }
    }

    // row sums: reduce across the 16 columns (lane bits 0..3)
    #pragma unroll
    for (int d = 1; d < 16; d <<= 1)
        #pragma unroll
        for (int mt = 0; mt < 4; ++mt)
            #pragma unroll
            for (int r = 0; r < 4; ++r)
                rs[mt][r] += __shfl_xor(rs[mt][r], d);

    // col sums: reduce across the 4 quads (lane bits 4..5)
    #pragma unroll
    for (int d = 16; d < 64; d <<= 1)
        #pragma unroll
        for (int nt = 0; nt < 4; ++nt)
            cs[nt] += __shfl_xor(cs[nt], d);

    if (lcol == 0) {
        #pragma unroll
        for (int mt = 0; mt < 4; ++mt)
            #pragma unroll
            for (int r = 0; r < 4; ++r)
                atomicAdd(&rowsum[row0 + wi + mt * 16 + q * 4 + r], rs[mt][r]);
    }
    if (q == 0) {
        #pragma unroll
        for (int nt = 0; nt < 4; ++nt)
            atomicAdd(&colsum[col0 + wj + nt * 16 + lcol], cs[nt]);
    }
}

// -------- final scalar: loss = mean_i( 2M + log(rowsum_i) + log(colsum_i) - 2*diag_i ) ----
__global__ __launch_bounds__(256) void finalize_kernel(
    const float* __restrict__ rowsum, const float* __restrict__ colsum,
    const float* __restrict__ diagv,  const float* __restrict__ temp_p,
    float* __restrict__ out)
{
    __shared__ float red[4];
    const float M = 1.0f / temp_p[0];
    const int i = blockIdx.x * 256 + threadIdx.x;
    float s = 2.f * M + logf(rowsum[i]) + logf(colsum[i]) - 2.f * diagv[i];
    #pragma unroll
    for (int d = 1; d < 64; d <<= 1) s += __shfl_xor(s, d);
    if ((threadIdx.x & 63) == 0) red[threadIdx.x >> 6] = s;
    __syncthreads();
    if (threadIdx.x == 0)
        atomicAdd(out, (red[0] + red[1] + red[2] + red[3]) / (float)NROWS);
}

extern "C" void kernel_launch(void* const* d_in, const int* in_sizes, int n_in,
                              void* d_out, int out_size, void* d_ws, size_t ws_size,
                              hipStream_t stream) {
    (void)in_sizes; (void)n_in; (void)out_size; (void)ws_size;
    const float* cxr    = (const float*)d_in[0];
    const float* ehr    = (const float*)d_in[1];
    const float* temp_p = (const float*)d_in[2];
    float* out = (float*)d_out;

    // workspace: rowsum[N] | colsum[N] | diag[N] | cn fp8 [N*512B] | en fp8 (~8.1 MB)
    float* rowsum = (float*)d_ws;
    float* colsum = rowsum + NROWS;
    float* diagv  = colsum + NROWS;
    uint32_t* cn8 = (uint32_t*)(diagv + NROWS);            // 16B-aligned (96 KB offset)
    uint32_t* en8 = cn8 + (size_t)NROWS * (DDIM / 4);
    const uint8_t* cnb = (const uint8_t*)cn8;
    const uint8_t* enb = (const uint8_t*)en8;

    prep_kernel<<<4096, 256, 0, stream>>>(cxr, ehr, cn8, en8, rowsum, out);
    gemm_loss_kernel<<<NBLK * NBLK, 256, 0, stream>>>(cnb, enb, temp_p, rowsum, colsum, diagv);
    finalize_kernel<<<NROWS / 256, 256, 0, stream>>>(rowsum, colsum, diagv, temp_p, out);
}